// Round 2
// baseline (4556.878 us; speedup 1.0000x reference)
//
#include <hip/hip_runtime.h>
#include <math.h>

#define T_LEN 512
#define BATCH 128
#define HID   256
#define BH    (BATCH*HID)   // 32768

// ---------------- helpers ----------------
// fast reciprocal: v_rcp_f32 + 1 Newton step (~0.5 ulp, way cheaper than exact div)
__device__ __forceinline__ float frcp(float d) {
    float r = __builtin_amdgcn_rcpf(d);
    return r * fmaf(-d, r, 2.0f);
}
__device__ __forceinline__ float sigmoid_f(float v) {
    return frcp(1.f + __expf(-v));
}
__device__ __forceinline__ float tanh_f(float v) {
    v = fminf(fmaxf(v, -15.f), 15.f);
    const float e = __expf(2.f * v);
    return (e - 1.f) * frcp(e + 1.f);
}
__device__ __forceinline__ float4 ldf4(const float* p) {
    return *reinterpret_cast<const float4*>(p);
}
__device__ __forceinline__ void fma4(float4& a, const float4 v, const float4 w) {
    a.x = fmaf(v.x, w.x, a.x);
    a.y = fmaf(v.y, w.y, a.y);
    a.z = fmaf(v.z, w.z, a.z);
    a.w = fmaf(v.w, w.w, a.w);
}
__device__ __forceinline__ float hsum4(const float4 a) {
    return (a.x + a.y) + (a.z + a.w);
}
// Stash a value in an AGPR (gfx950 unified RF; VALU can source AGPRs).
// An inline-asm def cannot be rematerialized -> the weight load happens ONCE.
// (Round-1 evidence: VGPR_Count=100 < 128 declared weight floats => the
// "pinned" VGPR weights were being re-streamed from L2/MALL every timestep.)
__device__ __forceinline__ float agpr(float v) {
    float a;
    asm("v_accvgpr_write_b32 %0, %1" : "=a"(a) : "v"(v));
    return a;
}
__device__ __forceinline__ float4 agpr4(const float4 v) {
    float4 r;
    r.x = agpr(v.x); r.y = agpr(v.y); r.z = agpr(v.z); r.w = agpr(v.w);
    return r;
}
// agent-scope relaxed atomics: coherent across XCDs, no cache flushes
__device__ __forceinline__ void astore(float* p, float v) {
    __hip_atomic_store(p, v, __ATOMIC_RELAXED, __HIP_MEMORY_SCOPE_AGENT);
}
__device__ __forceinline__ float2 af2(const float* p) {
    unsigned long long u = __hip_atomic_load((const unsigned long long*)p,
                                             __ATOMIC_RELAXED, __HIP_MEMORY_SCOPE_AGENT);
    union { unsigned long long u; float2 f; } c; c.u = u;
    return c.f;
}
__device__ __forceinline__ float4 af4(const float* p) {
    const float2 a = af2(p), b = af2(p + 2);
    return make_float4(a.x, a.y, b.x, b.y);
}
// DPP row_shr prefix reduction within 16-lane groups; lane (kc==15) gets the sum.
template<int CTRL>
__device__ __forceinline__ float dpp_mv(float x) {
    return __int_as_float(__builtin_amdgcn_update_dpp(
        0, __float_as_int(x), CTRL, 0xF, 0xF, true));
}
__device__ __forceinline__ float red16(float x) {
    x += dpp_mv<0x111>(x);  // row_shr:1
    x += dpp_mv<0x112>(x);  // row_shr:2
    x += dpp_mv<0x114>(x);  // row_shr:4
    x += dpp_mv<0x118>(x);  // row_shr:8
    return x;               // valid in lane kc==15 of each 16-group
}

// ---------------- persistent LSTM, AGPR-resident weights ----------------
// grid 512 x 256, 2 blocks/CU. XCD-swizzled decode: blocks sharing a
// (layer,jt) weight slice get bid = same (mod 8) -> same XCD -> slice stays
// in that XCD's L2 even if anything still streams.
// tid: jp = tid>>4 (one j), kc = tid&15 (K-chunk of 32 per 512-K half pair).
//
// Schedule (round-1 verified): L0 computes h0[s-1] at iter s (lag 1),
// L1 computes h1[s-3] (lag 3). Per iter: poll -> stage -> critical K=256
// recurrent GEMV (+ carried input-half partials + bias) -> OWNER-LANE
// epilogue (kc==15 holds all 4 gate sums; c lives in its registers)
// -> publish flag -> input-half GEMV for next step into per-lane ax[] regs
// (no reduction, no LDS: reduced jointly with crit next iteration).
__global__ __launch_bounds__(256)
__attribute__((amdgpu_waves_per_eu(2, 2)))
void lstm_persist(
    const float* __restrict__ x,
    const float* __restrict__ Wih, const float* __restrict__ Whh,
    const float* __restrict__ bih, const float* __restrict__ bhh,
    float* __restrict__ out,
    float* __restrict__ h0buf,   // 3 * BH (triple-buffered by timestep%3)
    float* __restrict__ h1buf,   // 3 * BH
    int* __restrict__ flags)     // 16 groups x 32 blocks
{
    __shared__ float ls_in[8 * 576];   // 8 b x 16 chunks x 36 (pad -> 2-way alias = free)

    const int tid = threadIdx.x;
    const int bid = blockIdx.x;
    // XCD-aware decode: weight-group g=(layer*16+jt) constant across the 16 bg
    // blocks; all blocks of one g share bid%8 -> same XCD (default round-robin).
    const int xcd = bid & 7;
    const int kk  = bid >> 3;              // 0..63
    const int g_  = xcd + 8 * (kk & 3);    // 0..31
    const int bg  = kk >> 2;               // 0..15
    const int layer = g_ >> 4;
    const int jt  = g_ & 15;
    const int jp = tid >> 4;
    const int kc = tid & 15;
    const int j = jt * 16 + jp;
    const int Bg0 = bg * 8;

    const float* Wih_l = Wih + (size_t)layer * 4 * HID * HID;
    const float* Whh_l = Whh + (size_t)layer * 4 * HID * HID;
    const float* bih_l = bih + layer * 4 * HID;
    const float* bhh_l = bhh + layer * 4 * HID;

    // Weights: 4 gates x 16 K-cols per half = 128 floats, ALL in AGPRs.
    float4 wih[4][4], whh[4][4];
    float bias[4];
    #pragma unroll
    for (int g = 0; g < 4; ++g) {
        const int row = g * HID + j;             // row in 4H
        const float* pih = Wih_l + (size_t)row * HID + kc * 16;
        const float* phh = Whh_l + (size_t)row * HID + kc * 16;
        #pragma unroll
        for (int m = 0; m < 4; ++m) {
            wih[g][m] = agpr4(ldf4(pih + m * 4));
            whh[g][m] = agpr4(ldf4(phh + m * 4));
        }
        bias[g] = bih_l[row] + bhh_l[row];
        asm volatile("" : "+v"(bias[g]));
    }

    // per-owner cell state (valid in kc==15 lanes) and carried input-half
    // per-lane partial sums (valid in all lanes, reduced next iteration).
    float c_reg[8];
    float ax[8][4];
    #pragma unroll
    for (int b = 0; b < 8; ++b) {
        c_reg[b] = 0.f;
        #pragma unroll
        for (int g = 0; g < 4; ++g) ax[b][g] = 0.f;
    }

    int* myflag = flags + bg * 32 + layer * 16 + jt;

    #pragma unroll 1
    for (int s = 0; s <= T_LEN + 2; ++s) {
        if (s > 0 && tid < 32) {
            // signed compare: 0xAAAAAAAA poison is negative -> blocks until real store
            const int thr = (layer == 0 && tid >= 16) ? (s - 1) : s;
            const int* f = flags + bg * 32 + tid;
            while (__hip_atomic_load(f, __ATOMIC_RELAXED, __HIP_MEMORY_SCOPE_AGENT) < thr)
                __builtin_amdgcn_s_sleep(1);
        }
        __syncthreads();   // everyone past poll; inputs published & visible

        // crit: compute h[t] (t = s-1 for L0, s-3 for L1) from recurrent half.
        // xact: input-half partial sums for the step after t (per-lane, in regs).
        const bool crit = (layer == 0) ? (s >= 1 && s <= T_LEN) : (s >= 3);
        const bool xact = (layer == 0) ? (s < T_LEN) : (s >= 2 && s <= T_LEN + 1);
        const bool zeroh = (layer == 0) ? (s == 1) : (s == 3);   // h[t-1] = 0

        if (crit || xact) {
            // ls_in layout: [b][cols 0..255 = input half | 256..511 = recurrent half]
            const float* ph0 = h0buf + (size_t)((s + 1) % 3) * BH;  // h0[s-2]
            const float* ph1 = h1buf + (size_t)((s + 2) % 3) * BH;  // h1[s-4]
            #pragma unroll
            for (int i = 0; i < 4; ++i) {
                const int F = tid + 256 * i;     // f4 index in 8x128
                const int b = F >> 7;
                const int rr = F & 127;
                const int col = (rr & 63) * 4;
                const size_t row = (size_t)(Bg0 + b) * HID + col;
                float4 v = make_float4(0.f, 0.f, 0.f, 0.f);
                if ((rr >> 6) == 0) {            // input half (slack)
                    if (xact)
                        v = (layer == 0) ? ldf4(x + (size_t)s * BH + row)
                                         : af4(ph0 + row);
                } else if (crit && !zeroh) {     // recurrent half (critical)
                    v = (layer == 0) ? af4(ph0 + row) : af4(ph1 + row);
                }
                *(float4*)(ls_in + b * 576 + (rr >> 3) * 36 + (rr & 7) * 4) = v;
            }
        }
        __syncthreads();   // staging visible

        const int lofs = (kc >> 1) * 36 + (kc & 1) * 16;

        if (crit) {
            const int t = (layer == 0) ? (s - 1) : (s - 3);
            float* hst = (layer == 0) ? (h0buf + (size_t)((s + 2) % 3) * BH)  // h0[s-1]
                                      : (h1buf + (size_t)(s % 3) * BH);       // h1[s-3]
            const bool last = (t == T_LEN - 1);
            // ---- CRITICAL: recurrent K=256 GEMV + joint reduce + owner epilogue
            #pragma unroll
            for (int b = 0; b < 8; ++b) {
                const float4* Lp = (const float4*)(ls_in + b * 576 + 288 + lofs);
                float4 i0 = Lp[0], i1 = Lp[1], i2 = Lp[2], i3 = Lp[3];
                float4 ac[4];
                #pragma unroll
                for (int g = 0; g < 4; ++g) ac[g] = make_float4(0.f, 0.f, 0.f, 0.f);
                #pragma unroll
                for (int g = 0; g < 4; ++g) {
                    fma4(ac[g], i0, whh[g][0]);
                    fma4(ac[g], i1, whh[g][1]);
                    fma4(ac[g], i2, whh[g][2]);
                    fma4(ac[g], i3, whh[g][3]);
                }
                // add carried input-half partial BEFORE the cross-lane reduce
                const float r0 = red16(hsum4(ac[0]) + ax[b][0]);
                const float r1 = red16(hsum4(ac[1]) + ax[b][1]);
                const float r2 = red16(hsum4(ac[2]) + ax[b][2]);
                const float r3 = red16(hsum4(ac[3]) + ax[b][3]);
                if (kc == 15) {   // owner lane: full epilogue, c in registers
                    const float gi = sigmoid_f(r0 + bias[0]);
                    const float gf = sigmoid_f(r1 + bias[1]);
                    const float gg = tanh_f   (r2 + bias[2]);
                    const float go = sigmoid_f(r3 + bias[3]);
                    const float cnew = fmaf(gf, c_reg[b], gi * gg);
                    c_reg[b] = cnew;
                    const float h = go * tanh_f(cnew);
                    const int B = Bg0 + b;
                    astore(hst + (size_t)B * HID + j, h);
                    if (layer == 1)
                        out[(size_t)t * BH + (size_t)B * HID + j] = h;
                    if (last) {
                        float* hn  = out + (size_t)T_LEN * BH;
                        float* cnp = hn + 2 * BH;
                        hn [(size_t)layer * BH + (size_t)B * HID + j] = h;
                        cnp[(size_t)layer * BH + (size_t)B * HID + j] = cnew;
                    }
                }
            }
        }
        __syncthreads();   // all owner h-stores drained (vmcnt(0) before s_barrier)
        if (s <= T_LEN + 1 && tid == 0)
            __hip_atomic_store(myflag, s + 1, __ATOMIC_RELAXED, __HIP_MEMORY_SCOPE_AGENT);

        if (xact) {
            // ---- SLACK: input-half K=256 GEMV for the NEXT step, in the
            // publish->poll window. Per-lane partials only; no reduce, no LDS.
            #pragma unroll
            for (int b = 0; b < 8; ++b) {
                const float4* Lp = (const float4*)(ls_in + b * 576 + lofs);
                float4 i0 = Lp[0], i1 = Lp[1], i2 = Lp[2], i3 = Lp[3];
                float4 ac[4];
                #pragma unroll
                for (int g = 0; g < 4; ++g) ac[g] = make_float4(0.f, 0.f, 0.f, 0.f);
                #pragma unroll
                for (int g = 0; g < 4; ++g) {
                    fma4(ac[g], i0, wih[g][0]);
                    fma4(ac[g], i1, wih[g][1]);
                    fma4(ac[g], i2, wih[g][2]);
                    fma4(ac[g], i3, wih[g][3]);
                }
                #pragma unroll
                for (int g = 0; g < 4; ++g) ax[b][g] = hsum4(ac[g]);
            }
        }
    }
}

extern "C" void kernel_launch(void* const* d_in, const int* in_sizes, int n_in,
                              void* d_out, int out_size, void* d_ws, size_t ws_size,
                              hipStream_t stream) {
    const float* x   = (const float*)d_in[0];
    const float* Wih = (const float*)d_in[1];
    const float* Whh = (const float*)d_in[2];
    const float* bih = (const float*)d_in[3];
    const float* bhh = (const float*)d_in[4];
    float* out = (float*)d_out;

    float* h0 = (float*)d_ws;          // 3*BH
    float* h1 = h0 + 3 * BH;           // 3*BH
    int* flags = (int*)(h1 + 3 * BH);  // 512 ints, poison-proof (signed compare)

    hipLaunchKernelGGL(lstm_persist, dim3(512), dim3(256), 0, stream,
                       x, Wih, Whh, bih, bhh, out, h0, h1, flags);
}